// Round 7
// baseline (621.436 us; speedup 1.0000x reference)
//
#include <hip/hip_runtime.h>
#include <hip/hip_bf16.h>
#include <cstdint>

typedef unsigned short u16;
typedef __attribute__((ext_vector_type(8))) __bf16 bf16x8;
typedef __attribute__((ext_vector_type(4))) float f32x4;

#define NN 131072
#define C 64
#define KNB 27
#define EMB 512
#define NGROUP 32
#define GN_EPS 1e-5f
#define NBLK 512

__device__ __forceinline__ void gload_lds16(const void* gsrc, void* ldsdst) {
    __builtin_amdgcn_global_load_lds(
        (const __attribute__((address_space(1))) char*)(unsigned long long)(uintptr_t)gsrc,
        (__attribute__((address_space(3))) char*)(unsigned int)(uintptr_t)ldsdst,
        16, 0, 0);
}

__device__ __forceinline__ float silu_f(float x) {
    return x / (1.0f + __expf(-x));
}

__device__ __forceinline__ u16 f2bf(float x) {
    __hip_bfloat16 h = __float2bfloat16(x);
    return __builtin_bit_cast(u16, h);
}

__device__ __forceinline__ float bf2f(u16 h) {
    unsigned u = ((unsigned)h) << 16;
    return __builtin_bit_cast(float, u);
}

__device__ __forceinline__ unsigned pack2(float a, float b) {
    return (unsigned)f2bf(a) | ((unsigned)f2bf(b) << 16);
}

// Software grid barrier: one arrival per block; spin with device-scope acquire.
// Safe because grid(512) <= total residency capacity (>=2 blocks/CU by LDS/VGPR/waves).
__device__ __forceinline__ void grid_barrier(unsigned* ctr) {
    __syncthreads();
    if (threadIdx.x == 0) {
        __threadfence(); // release prior writes device-wide
        __hip_atomic_fetch_add(ctr, 1u, __ATOMIC_ACQ_REL, __HIP_MEMORY_SCOPE_AGENT);
        while (__hip_atomic_load(ctr, __ATOMIC_ACQUIRE, __HIP_MEMORY_SCOPE_AGENT) < NBLK) {
            __builtin_amdgcn_s_sleep(16);
        }
        __threadfence(); // acquire: invalidate stale caches before consuming
    }
    __syncthreads();
}

struct MegaArgs {
    const float* x;
    const float* time_emb;
    const int* batch_id;
    const int* neigh;
    const float* g1; const float* be1;
    const float* W1; const float* b1;
    const float* Wt; const float* bt;
    const float* g2; const float* be2;
    const float* W2; const float* b2;
    u16* Wb1; u16* Wb2;
    float* tvec;
    float* stats1; float* cnt1;
    float* stats2; float* cnt2;
    unsigned* bar;
    u16* h1; u16* h2; u16* h3;
    float* out;
};

// ---------- conv body: A gathered to regs (depth-2, mod-3 queue), W phase-LDS ----------
// Block 512 thr (8 waves), wave = 32 nodes x 64 co, block = 256 nodes.
template <bool ADD_T, bool FUSE_STATS, bool OUT_F32_RES>
__device__ __forceinline__ void conv_body(
    const u16* __restrict__ act, const int* __restrict__ neigh,
    const u16* __restrict__ Wb, const float* __restrict__ bias,
    const float* __restrict__ tvec, const int* __restrict__ batch_id,
    const float* __restrict__ resid, void* __restrict__ outp,
    float* __restrict__ stats, float* __restrict__ cnt, u16* Wbuf) {
    float* shs = (float*)Wbuf;
    const int tid = threadIdx.x;
    const int w = tid >> 6, lane = tid & 63;
    const int q = lane >> 4, m = lane & 15;
    const int n0 = blockIdx.x * 256;
    const int nw = n0 + w * 32;

    const int* nrow0 = neigh + (size_t)(nw + m) * KNB;
    const int* nrow1 = neigh + (size_t)(nw + 16 + m) * KNB;

    f32x4 acc[2][4] = {};
    bf16x8 aB[3][2][2];
    int offn0, offn1;

    {
        int o0 = nrow0[0] * C, o1 = nrow1[0] * C;
        aB[0][0][0] = *(const bf16x8*)(act + o0 + q * 8);
        aB[0][0][1] = *(const bf16x8*)(act + o0 + 32 + q * 8);
        aB[0][1][0] = *(const bf16x8*)(act + o1 + q * 8);
        aB[0][1][1] = *(const bf16x8*)(act + o1 + 32 + q * 8);
        o0 = nrow0[1] * C; o1 = nrow1[1] * C;
        aB[1][0][0] = *(const bf16x8*)(act + o0 + q * 8);
        aB[1][0][1] = *(const bf16x8*)(act + o0 + 32 + q * 8);
        aB[1][1][0] = *(const bf16x8*)(act + o1 + q * 8);
        aB[1][1][1] = *(const bf16x8*)(act + o1 + 32 + q * 8);
        offn0 = nrow0[2] * C;
        offn1 = nrow1[2] * C;
    }

    // phases of 6/6/6/6/3 k-slices; phase starts divisible by 3 -> k%3 == sI%3
#pragma unroll
    for (int phase = 0; phase < 5; ++phase) {
        const int k0 = phase * 6;
        const int nk = (phase == 4) ? 3 : 6;
        if (phase) __syncthreads(); // prior phase's Wbuf reads done
        const int total = nk * 512;
#pragma unroll
        for (int it = 0; it < 6; ++it) {
            int cb = it * 512 + w * 64; // wave-uniform chunk base
            if (cb < total) {
                int cc = cb + lane;
                int rr = cc >> 3;
                int pos = cc & 7;
                int srcc = pos ^ (rr & 7);
                gload_lds16(Wb + (((k0 << 6) + rr) << 6) + (srcc << 3), Wbuf + cb * 8);
            }
        }
        __syncthreads(); // W visible

#pragma unroll
        for (int sI = 0; sI < nk; ++sI) {
            const int k = k0 + sI;
            const int use = sI % 3;        // == k%3
            const int nxt = (sI + 2) % 3;  // == (k+2)%3
            if (k + 2 < KNB) {
                aB[nxt][0][0] = *(const bf16x8*)(act + offn0 + q * 8);
                aB[nxt][0][1] = *(const bf16x8*)(act + offn0 + 32 + q * 8);
                aB[nxt][1][0] = *(const bf16x8*)(act + offn1 + q * 8);
                aB[nxt][1][1] = *(const bf16x8*)(act + offn1 + 32 + q * 8);
            }
            if (k + 3 < KNB) {
                offn0 = nrow0[k + 3] * C;
                offn1 = nrow1[k + 3] * C;
            }
            const u16* wsl = Wbuf + sI * 4096;
#pragma unroll
            for (int kk = 0; kk < 2; ++kk) {
#pragma unroll
                for (int j = 0; j < 4; ++j) {
                    const int co = j * 16 + m;
                    const int lc = kk * 4 + q;
                    bf16x8 b = *(const bf16x8*)(wsl + (co << 6) + ((lc ^ (co & 7)) << 3));
                    acc[0][j] = __builtin_amdgcn_mfma_f32_16x16x32_bf16(aB[use][0][kk], b, acc[0][j], 0, 0, 0);
                    acc[1][j] = __builtin_amdgcn_mfma_f32_16x16x32_bf16(aB[use][1][kk], b, acc[1][j], 0, 0, 0);
                }
            }
        }
    }

    // ---- epilogue: bias (+temb), store; D: col=m (co j*16+m), row=q*4+reg ----
    float bs[4];
#pragma unroll
    for (int j = 0; j < 4; ++j) bs[j] = bias[j * 16 + m];

#pragma unroll
    for (int s = 0; s < 2; ++s) {
#pragma unroll
        for (int reg = 0; reg < 4; ++reg) {
            const int n = nw + s * 16 + q * 4 + reg;
            int b = 0;
            if (ADD_T) b = batch_id[n];
#pragma unroll
            for (int j = 0; j < 4; ++j) {
                const int co = j * 16 + m;
                float v = acc[s][j][reg] + bs[j];
                if (ADD_T) v += tvec[b * C + co];
                acc[s][j][reg] = v;
                if (OUT_F32_RES) {
                    ((float*)outp)[(size_t)n * C + co] = v + resid[(size_t)n * C + co];
                } else {
                    ((u16*)outp)[(size_t)n * C + co] = f2bf(v);
                }
            }
        }
    }

    if (FUSE_STATS) {
        __syncthreads(); // all waves done with Wbuf -> reuse as stats scratch
        for (int i = tid; i < 520; i += 512) shs[i] = 0.f;
        __syncthreads();
        const int blo = batch_id[nw], bhi = batch_id[nw + 31];
        if (blo == bhi) {
#pragma unroll
            for (int j = 0; j < 4; ++j) {
                float s = 0.f, ss = 0.f;
#pragma unroll
                for (int sq = 0; sq < 2; ++sq)
#pragma unroll
                    for (int reg = 0; reg < 4; ++reg) {
                        float v = acc[sq][j][reg];
                        s += v; ss += v * v;
                    }
                s += __shfl_xor(s, 16, 64);  ss += __shfl_xor(ss, 16, 64);
                s += __shfl_xor(s, 32, 64);  ss += __shfl_xor(ss, 32, 64);
                s += __shfl_xor(s, 1, 64);   ss += __shfl_xor(ss, 1, 64);
                if (q == 0 && (m & 1) == 0) {
                    int g = (j * 16 + m) >> 1;
                    atomicAdd(&shs[(blo * NGROUP + g) * 2 + 0], s);
                    atomicAdd(&shs[(blo * NGROUP + g) * 2 + 1], ss);
                }
            }
        } else {
#pragma unroll
            for (int sq = 0; sq < 2; ++sq)
#pragma unroll
                for (int reg = 0; reg < 4; ++reg) {
                    int b = batch_id[nw + sq * 16 + q * 4 + reg];
#pragma unroll
                    for (int j = 0; j < 4; ++j) {
                        int g = (j * 16 + m) >> 1;
                        float v = acc[sq][j][reg];
                        atomicAdd(&shs[(b * NGROUP + g) * 2 + 0], v);
                        atomicAdd(&shs[(b * NGROUP + g) * 2 + 1], v * v);
                    }
                }
        }
        if (tid < 256) atomicAdd(&shs[512 + batch_id[n0 + tid]], 1.0f);
        __syncthreads();
        if (tid < 512 && shs[tid] != 0.f) atomicAdd(&stats[tid], shs[tid]);
        if (tid < 8 && shs[512 + tid] != 0.f) atomicAdd(&cnt[tid], shs[512 + tid]);
    }
}

// ---------- gn apply bodies (grid-stride, 8 ch/item) ----------
__device__ __forceinline__ void gn_apply_f32_body(
    const float* __restrict__ x, const int* __restrict__ batch_id,
    const float* __restrict__ stats, const float* __restrict__ cnt,
    const float* __restrict__ gamma, const float* __restrict__ beta,
    u16* __restrict__ out) {
    const int gstride = NBLK * 512;
    for (int idx = blockIdx.x * 512 + threadIdx.x; idx < NN * 8; idx += gstride) {
        int n = idx >> 3, seg = idx & 7;
        int b = batch_id[n];
        float denom = cnt[b] * 2.0f;
        float4 v0 = *(const float4*)(x + (size_t)n * C + seg * 8);
        float4 v1 = *(const float4*)(x + (size_t)n * C + seg * 8 + 4);
        float4 ga0 = *(const float4*)(gamma + seg * 8);
        float4 ga1 = *(const float4*)(gamma + seg * 8 + 4);
        float4 be0 = *(const float4*)(beta + seg * 8);
        float4 be1 = *(const float4*)(beta + seg * 8 + 4);
        float mn[4], rs[4];
#pragma unroll
        for (int p = 0; p < 4; ++p) {
            float2 st = *(const float2*)(stats + (b * NGROUP + seg * 4 + p) * 2);
            float mean = st.x / denom;
            float var = st.y / denom - mean * mean;
            mn[p] = mean;
            rs[p] = rsqrtf(var + GN_EPS);
        }
        float y0 = silu_f((v0.x - mn[0]) * rs[0] * ga0.x + be0.x);
        float y1 = silu_f((v0.y - mn[0]) * rs[0] * ga0.y + be0.y);
        float y2 = silu_f((v0.z - mn[1]) * rs[1] * ga0.z + be0.z);
        float y3 = silu_f((v0.w - mn[1]) * rs[1] * ga0.w + be0.w);
        float y4 = silu_f((v1.x - mn[2]) * rs[2] * ga1.x + be1.x);
        float y5 = silu_f((v1.y - mn[2]) * rs[2] * ga1.y + be1.y);
        float y6 = silu_f((v1.z - mn[3]) * rs[3] * ga1.z + be1.z);
        float y7 = silu_f((v1.w - mn[3]) * rs[3] * ga1.w + be1.w);
        uint4 o;
        o.x = pack2(y0, y1); o.y = pack2(y2, y3); o.z = pack2(y4, y5); o.w = pack2(y6, y7);
        *(uint4*)(out + (size_t)n * C + seg * 8) = o;
    }
}

__device__ __forceinline__ void gn_apply_bf16_body(
    const u16* __restrict__ x, const int* __restrict__ batch_id,
    const float* __restrict__ stats, const float* __restrict__ cnt,
    const float* __restrict__ gamma, const float* __restrict__ beta,
    u16* __restrict__ out) {
    const int gstride = NBLK * 512;
    for (int idx = blockIdx.x * 512 + threadIdx.x; idx < NN * 8; idx += gstride) {
        int n = idx >> 3, seg = idx & 7;
        int b = batch_id[n];
        float denom = cnt[b] * 2.0f;
        uint4 u = *(const uint4*)(x + (size_t)n * C + seg * 8);
        float4 ga0 = *(const float4*)(gamma + seg * 8);
        float4 ga1 = *(const float4*)(gamma + seg * 8 + 4);
        float4 be0 = *(const float4*)(beta + seg * 8);
        float4 be1 = *(const float4*)(beta + seg * 8 + 4);
        float mn[4], rs[4];
#pragma unroll
        for (int p = 0; p < 4; ++p) {
            float2 st = *(const float2*)(stats + (b * NGROUP + seg * 4 + p) * 2);
            float mean = st.x / denom;
            float var = st.y / denom - mean * mean;
            mn[p] = mean;
            rs[p] = rsqrtf(var + GN_EPS);
        }
        float v0 = bf2f(u.x & 0xffff), v1 = bf2f(u.x >> 16);
        float v2 = bf2f(u.y & 0xffff), v3 = bf2f(u.y >> 16);
        float v4 = bf2f(u.z & 0xffff), v5 = bf2f(u.z >> 16);
        float v6 = bf2f(u.w & 0xffff), v7 = bf2f(u.w >> 16);
        float y0 = silu_f((v0 - mn[0]) * rs[0] * ga0.x + be0.x);
        float y1 = silu_f((v1 - mn[0]) * rs[0] * ga0.y + be0.y);
        float y2 = silu_f((v2 - mn[1]) * rs[1] * ga0.z + be0.z);
        float y3 = silu_f((v3 - mn[1]) * rs[1] * ga0.w + be0.w);
        float y4 = silu_f((v4 - mn[2]) * rs[2] * ga1.x + be1.x);
        float y5 = silu_f((v5 - mn[2]) * rs[2] * ga1.y + be1.y);
        float y6 = silu_f((v6 - mn[3]) * rs[3] * ga1.z + be1.z);
        float y7 = silu_f((v7 - mn[3]) * rs[3] * ga1.w + be1.w);
        uint4 o;
        o.x = pack2(y0, y1); o.y = pack2(y2, y3); o.z = pack2(y4, y5); o.w = pack2(y6, y7);
        *(uint4*)(out + (size_t)n * C + seg * 8) = o;
    }
}

// ---------- the single mega kernel (software grid barriers) ----------
__global__ __launch_bounds__(512, 4) void mega_kernel(MegaArgs a) {
    __shared__ u16 Wbuf[6 * 64 * 64]; // 49152 B (also reused as float scratch)
    float* shf = (float*)Wbuf;
    const int bid = blockIdx.x;
    const int t = threadIdx.x;

    // ================= P0: W-prep / time-MLP / gn1 stats =================
    if (bid < 108) {
        const int per = KNB * C * C; // 110592
        int e0 = (bid * 512 + t) * 4;
#pragma unroll
        for (int d = 0; d < 4; ++d) {
            int idx = e0 + d;
            const float* src = (idx < per) ? a.W1 : a.W2;
            u16* dst = (idx < per) ? a.Wb1 : a.Wb2;
            int e = (idx < per) ? idx : idx - per;
            int k = e >> 12;
            int rem = e & 4095;
            int co = rem >> 6;
            int ci = rem & 63;
            dst[e] = f2bf(src[(k * C + ci) * C + co]);
        }
    } else if (bid < 116) {
        int b = bid - 108;
        int co = t & 63, seg = t >> 6; // seg 0..7
        float acc = 0.f;
        for (int i = 0; i < 64; ++i) {
            int e = seg * 64 + i;
            float v = a.time_emb[b * EMB + e];
            acc += silu_f(v) * a.Wt[e * C + co];
        }
        shf[t] = acc;
        __syncthreads();
        if (t < 64) {
            float s = a.bt[t];
#pragma unroll
            for (int j = 0; j < 8; ++j) s += shf[t + 64 * j];
            a.tvec[b * C + t] = s;
        }
    }
    __syncthreads();
    // gn1 stats: every block handles 256 nodes
    {
        for (int i = t; i < 520; i += 512) shf[i] = 0.f;
        __syncthreads();
        const int n0s = bid * 256;
        const int c4 = t & 15, r = t >> 4; // r 0..31
        float s0 = 0.f, ss0 = 0.f, s1 = 0.f, ss1 = 0.f, c = 0.f;
        int cur = -1;
        for (int i = 0; i < 8; ++i) {
            int n = n0s + i * 32 + r;
            int b = a.batch_id[n];
            if (b != cur) {
                if (cur >= 0) {
                    int g0 = 2 * c4;
                    atomicAdd(&shf[(cur * NGROUP + g0) * 2 + 0], s0);
                    atomicAdd(&shf[(cur * NGROUP + g0) * 2 + 1], ss0);
                    atomicAdd(&shf[(cur * NGROUP + g0 + 1) * 2 + 0], s1);
                    atomicAdd(&shf[(cur * NGROUP + g0 + 1) * 2 + 1], ss1);
                    if (c4 == 0) atomicAdd(&shf[512 + cur], c);
                }
                cur = b; s0 = ss0 = s1 = ss1 = c = 0.f;
            }
            float4 v = *(const float4*)(a.x + (size_t)n * C + c4 * 4);
            s0 += v.x + v.y;  ss0 += v.x * v.x + v.y * v.y;
            s1 += v.z + v.w;  ss1 += v.z * v.z + v.w * v.w;
            c += 1.f;
        }
        {
            int g0 = 2 * c4;
            atomicAdd(&shf[(cur * NGROUP + g0) * 2 + 0], s0);
            atomicAdd(&shf[(cur * NGROUP + g0) * 2 + 1], ss0);
            atomicAdd(&shf[(cur * NGROUP + g0 + 1) * 2 + 0], s1);
            atomicAdd(&shf[(cur * NGROUP + g0 + 1) * 2 + 1], ss1);
            if (c4 == 0) atomicAdd(&shf[512 + cur], c);
        }
        __syncthreads();
        if (t < 512 && shf[t] != 0.f) atomicAdd(&a.stats1[t], shf[t]);
        if (t < 8 && shf[512 + t] != 0.f) atomicAdd(&a.cnt1[t], shf[512 + t]);
    }

    grid_barrier(a.bar + 0);
    // ================= P1: gn1 apply x -> h1 (bf16) =================
    gn_apply_f32_body(a.x, a.batch_id, a.stats1, a.cnt1, a.g1, a.be1, a.h1);

    grid_barrier(a.bar + 16);
    // ================= P2: conv1 (+temb, +fused gn2 stats) -> h2 bf16 =================
    conv_body<true, true, false>(a.h1, a.neigh, a.Wb1, a.b1, a.tvec, a.batch_id,
                                 nullptr, (void*)a.h2, a.stats2, a.cnt2, Wbuf);

    grid_barrier(a.bar + 32);
    // ================= P3: gn2 apply h2 -> h3 (bf16) =================
    gn_apply_bf16_body(a.h2, a.batch_id, a.stats2, a.cnt2, a.g2, a.be2, a.h3);

    grid_barrier(a.bar + 48);
    // ================= P4: conv2 + residual -> out fp32 =================
    conv_body<false, false, true>(a.h3, a.neigh, a.Wb2, a.b2, nullptr, a.batch_id,
                                  a.x, (void*)a.out, nullptr, nullptr, Wbuf);
}

extern "C" void kernel_launch(void* const* d_in, const int* in_sizes, int n_in,
                              void* d_out, int out_size, void* d_ws, size_t ws_size,
                              hipStream_t stream) {
    char* ws = (char*)d_ws;
    MegaArgs a;
    a.x        = (const float*)d_in[0];
    a.time_emb = (const float*)d_in[1];
    a.batch_id = (const int*)d_in[2];
    a.neigh    = (const int*)d_in[3];
    a.g1       = (const float*)d_in[4];
    a.be1      = (const float*)d_in[5];
    a.W1       = (const float*)d_in[6];
    a.b1       = (const float*)d_in[7];
    a.Wt       = (const float*)d_in[8];
    a.bt       = (const float*)d_in[9];
    a.g2       = (const float*)d_in[10];
    a.be2      = (const float*)d_in[11];
    a.W2       = (const float*)d_in[12];
    a.b2       = (const float*)d_in[13];
    a.h1     = (u16*)(ws + 0);            // 16 MB
    a.h2     = (u16*)(ws + 16777216);     // 16 MB
    a.h3     = (u16*)(ws + 33554432);     // 16 MB
    a.Wb1    = (u16*)(ws + 50331648);     // 221184 B
    a.Wb2    = (u16*)(ws + 50552832);     // 221184 B
    a.tvec   = (float*)(ws + 50774016);   // 2048 B, ends 50776064
    a.stats1 = (float*)(ws + 50776064);   // 512 f, ends 50778112
    a.cnt1   = a.stats1 + 512;            // 8 f,   ends 50778144
    a.stats2 = a.cnt1 + 8;                // 512 f, ends 50780192
    a.cnt2   = a.stats2 + 512;            // 8 f,   ends 50780224
    a.bar    = (unsigned*)(ws + 50780224); // 64 u32, ends 50780480 (CONTIGUOUS - covered by memset)
    a.out    = (float*)d_out;

    // zero stats (1040 floats) + barrier counters (64 uints) = 4416 bytes, one contiguous range
    hipMemsetAsync(ws + 50776064, 0, 4416, stream);
    mega_kernel<<<NBLK, 512, 0, stream>>>(a);
}

// Round 8
// 513.484 us; speedup vs baseline: 1.2102x; 1.2102x over previous
//
#include <hip/hip_runtime.h>
#include <hip/hip_bf16.h>
#include <cstdint>

typedef unsigned short u16;
typedef __attribute__((ext_vector_type(8))) __bf16 bf16x8;
typedef __attribute__((ext_vector_type(4))) float f32x4;

#define NN 131072
#define C 64
#define KNB 27
#define EMB 512
#define NGROUP 32
#define GN_EPS 1e-5f
#define NBLK 512

__device__ __forceinline__ void gload_lds16(const void* gsrc, void* ldsdst) {
    __builtin_amdgcn_global_load_lds(
        (const __attribute__((address_space(1))) char*)(unsigned long long)(uintptr_t)gsrc,
        (__attribute__((address_space(3))) char*)(unsigned int)(uintptr_t)ldsdst,
        16, 0, 0);
}

__device__ __forceinline__ float silu_f(float x) {
    return x / (1.0f + __expf(-x));
}

__device__ __forceinline__ u16 f2bf(float x) {
    __hip_bfloat16 h = __float2bfloat16(x);
    return __builtin_bit_cast(u16, h);
}

__device__ __forceinline__ float bf2f(u16 h) {
    unsigned u = ((unsigned)h) << 16;
    return __builtin_bit_cast(float, u);
}

__device__ __forceinline__ unsigned pack2(float a, float b) {
    return (unsigned)f2bf(a) | ((unsigned)f2bf(b) << 16);
}

// Software grid barrier. Spin with RELAXED loads (no cache invalidation per poll);
// exactly one release fence before arrival and one acquire fence after completion.
// Safe: grid(512) <= residency capacity (>=2 blocks/CU by LDS/VGPR/waves).
__device__ __forceinline__ void grid_barrier(unsigned* ctr) {
    __syncthreads();
    if (threadIdx.x == 0) {
        __threadfence(); // release: make prior writes visible device-wide (once)
        __hip_atomic_fetch_add(ctr, 1u, __ATOMIC_RELAXED, __HIP_MEMORY_SCOPE_AGENT);
        while (__hip_atomic_load(ctr, __ATOMIC_RELAXED, __HIP_MEMORY_SCOPE_AGENT) < NBLK) {
            __builtin_amdgcn_s_sleep(16);
        }
        __threadfence(); // acquire: invalidate stale caches (once)
    }
    __syncthreads();
}

struct MegaArgs {
    const float* x;
    const float* time_emb;
    const int* batch_id;
    const int* neigh;
    const float* g1; const float* be1;
    const float* W1; const float* b1;
    const float* Wt; const float* bt;
    const float* g2; const float* be2;
    const float* W2; const float* b2;
    u16* Wb1; u16* Wb2;
    float* tvec;
    float* stats1; float* cnt1;
    float* stats2; float* cnt2;
    unsigned* bar;
    u16* h1; u16* h2; u16* h3;
    float* out;
};

// ---------- conv body: A gathered to regs (depth-2, mod-3 queue), W phase-LDS ----------
// Block 512 thr (8 waves), wave = 32 nodes x 64 co, block = 256 nodes.
template <bool ADD_T, bool FUSE_STATS, bool OUT_F32_RES>
__device__ __forceinline__ void conv_body(
    const u16* __restrict__ act, const int* __restrict__ neigh,
    const u16* __restrict__ Wb, const float* __restrict__ bias,
    const float* __restrict__ tvec, const int* __restrict__ batch_id,
    const float* __restrict__ resid, void* __restrict__ outp,
    float* __restrict__ stats, float* __restrict__ cnt, u16* Wbuf) {
    float* shs = (float*)Wbuf;
    const int tid = threadIdx.x;
    const int w = tid >> 6, lane = tid & 63;
    const int q = lane >> 4, m = lane & 15;
    const int n0 = blockIdx.x * 256;
    const int nw = n0 + w * 32;

    const int* nrow0 = neigh + (size_t)(nw + m) * KNB;
    const int* nrow1 = neigh + (size_t)(nw + 16 + m) * KNB;

    f32x4 acc[2][4] = {};
    bf16x8 aB[3][2][2];
    int offn0, offn1;

    {
        int o0 = nrow0[0] * C, o1 = nrow1[0] * C;
        aB[0][0][0] = *(const bf16x8*)(act + o0 + q * 8);
        aB[0][0][1] = *(const bf16x8*)(act + o0 + 32 + q * 8);
        aB[0][1][0] = *(const bf16x8*)(act + o1 + q * 8);
        aB[0][1][1] = *(const bf16x8*)(act + o1 + 32 + q * 8);
        o0 = nrow0[1] * C; o1 = nrow1[1] * C;
        aB[1][0][0] = *(const bf16x8*)(act + o0 + q * 8);
        aB[1][0][1] = *(const bf16x8*)(act + o0 + 32 + q * 8);
        aB[1][1][0] = *(const bf16x8*)(act + o1 + q * 8);
        aB[1][1][1] = *(const bf16x8*)(act + o1 + 32 + q * 8);
        offn0 = nrow0[2] * C;
        offn1 = nrow1[2] * C;
    }

    // phases of 6/6/6/6/3 k-slices; phase starts divisible by 3 -> k%3 == sI%3
#pragma unroll
    for (int phase = 0; phase < 5; ++phase) {
        const int k0 = phase * 6;
        const int nk = (phase == 4) ? 3 : 6;
        if (phase) __syncthreads(); // prior phase's Wbuf reads done
        const int total = nk * 512;
#pragma unroll
        for (int it = 0; it < 6; ++it) {
            int cb = it * 512 + w * 64; // wave-uniform chunk base
            if (cb < total) {
                int cc = cb + lane;
                int rr = cc >> 3;
                int pos = cc & 7;
                int srcc = pos ^ (rr & 7);
                gload_lds16(Wb + (((k0 << 6) + rr) << 6) + (srcc << 3), Wbuf + cb * 8);
            }
        }
        __syncthreads(); // W visible

#pragma unroll
        for (int sI = 0; sI < nk; ++sI) {
            const int k = k0 + sI;
            const int use = sI % 3;        // == k%3
            const int nxt = (sI + 2) % 3;  // == (k+2)%3
            if (k + 2 < KNB) {
                aB[nxt][0][0] = *(const bf16x8*)(act + offn0 + q * 8);
                aB[nxt][0][1] = *(const bf16x8*)(act + offn0 + 32 + q * 8);
                aB[nxt][1][0] = *(const bf16x8*)(act + offn1 + q * 8);
                aB[nxt][1][1] = *(const bf16x8*)(act + offn1 + 32 + q * 8);
            }
            if (k + 3 < KNB) {
                offn0 = nrow0[k + 3] * C;
                offn1 = nrow1[k + 3] * C;
            }
            const u16* wsl = Wbuf + sI * 4096;
#pragma unroll
            for (int kk = 0; kk < 2; ++kk) {
#pragma unroll
                for (int j = 0; j < 4; ++j) {
                    const int co = j * 16 + m;
                    const int lc = kk * 4 + q;
                    bf16x8 b = *(const bf16x8*)(wsl + (co << 6) + ((lc ^ (co & 7)) << 3));
                    acc[0][j] = __builtin_amdgcn_mfma_f32_16x16x32_bf16(aB[use][0][kk], b, acc[0][j], 0, 0, 0);
                    acc[1][j] = __builtin_amdgcn_mfma_f32_16x16x32_bf16(aB[use][1][kk], b, acc[1][j], 0, 0, 0);
                }
            }
        }
    }

    // ---- epilogue: bias (+temb), store; D: col=m (co j*16+m), row=q*4+reg ----
    float bs[4];
#pragma unroll
    for (int j = 0; j < 4; ++j) bs[j] = bias[j * 16 + m];

#pragma unroll
    for (int s = 0; s < 2; ++s) {
#pragma unroll
        for (int reg = 0; reg < 4; ++reg) {
            const int n = nw + s * 16 + q * 4 + reg;
            int b = 0;
            if (ADD_T) b = batch_id[n];
#pragma unroll
            for (int j = 0; j < 4; ++j) {
                const int co = j * 16 + m;
                float v = acc[s][j][reg] + bs[j];
                if (ADD_T) v += tvec[b * C + co];
                acc[s][j][reg] = v;
                if (OUT_F32_RES) {
                    ((float*)outp)[(size_t)n * C + co] = v + resid[(size_t)n * C + co];
                } else {
                    ((u16*)outp)[(size_t)n * C + co] = f2bf(v);
                }
            }
        }
    }

    if (FUSE_STATS) {
        __syncthreads(); // all waves done with Wbuf -> reuse as stats scratch
        for (int i = tid; i < 520; i += 512) shs[i] = 0.f;
        __syncthreads();
        const int blo = batch_id[nw], bhi = batch_id[nw + 31];
        if (blo == bhi) {
#pragma unroll
            for (int j = 0; j < 4; ++j) {
                float s = 0.f, ss = 0.f;
#pragma unroll
                for (int sq = 0; sq < 2; ++sq)
#pragma unroll
                    for (int reg = 0; reg < 4; ++reg) {
                        float v = acc[sq][j][reg];
                        s += v; ss += v * v;
                    }
                s += __shfl_xor(s, 16, 64);  ss += __shfl_xor(ss, 16, 64);
                s += __shfl_xor(s, 32, 64);  ss += __shfl_xor(ss, 32, 64);
                s += __shfl_xor(s, 1, 64);   ss += __shfl_xor(ss, 1, 64);
                if (q == 0 && (m & 1) == 0) {
                    int g = (j * 16 + m) >> 1;
                    atomicAdd(&shs[(blo * NGROUP + g) * 2 + 0], s);
                    atomicAdd(&shs[(blo * NGROUP + g) * 2 + 1], ss);
                }
            }
        } else {
#pragma unroll
            for (int sq = 0; sq < 2; ++sq)
#pragma unroll
                for (int reg = 0; reg < 4; ++reg) {
                    int b = batch_id[nw + sq * 16 + q * 4 + reg];
#pragma unroll
                    for (int j = 0; j < 4; ++j) {
                        int g = (j * 16 + m) >> 1;
                        float v = acc[sq][j][reg];
                        atomicAdd(&shs[(b * NGROUP + g) * 2 + 0], v);
                        atomicAdd(&shs[(b * NGROUP + g) * 2 + 1], v * v);
                    }
                }
        }
        if (tid < 256) atomicAdd(&shs[512 + batch_id[n0 + tid]], 1.0f);
        __syncthreads();
        if (tid < 512 && shs[tid] != 0.f) atomicAdd(&stats[tid], shs[tid]);
        if (tid < 8 && shs[512 + tid] != 0.f) atomicAdd(&cnt[tid], shs[512 + tid]);
    }
}

// ---------- gn apply bodies (grid-stride, 8 ch/item) ----------
__device__ __forceinline__ void gn_apply_f32_body(
    const float* __restrict__ x, const int* __restrict__ batch_id,
    const float* __restrict__ stats, const float* __restrict__ cnt,
    const float* __restrict__ gamma, const float* __restrict__ beta,
    u16* __restrict__ out) {
    const int gstride = NBLK * 512;
    for (int idx = blockIdx.x * 512 + threadIdx.x; idx < NN * 8; idx += gstride) {
        int n = idx >> 3, seg = idx & 7;
        int b = batch_id[n];
        float denom = cnt[b] * 2.0f;
        float4 v0 = *(const float4*)(x + (size_t)n * C + seg * 8);
        float4 v1 = *(const float4*)(x + (size_t)n * C + seg * 8 + 4);
        float4 ga0 = *(const float4*)(gamma + seg * 8);
        float4 ga1 = *(const float4*)(gamma + seg * 8 + 4);
        float4 be0 = *(const float4*)(beta + seg * 8);
        float4 be1 = *(const float4*)(beta + seg * 8 + 4);
        float mn[4], rs[4];
#pragma unroll
        for (int p = 0; p < 4; ++p) {
            float2 st = *(const float2*)(stats + (b * NGROUP + seg * 4 + p) * 2);
            float mean = st.x / denom;
            float var = st.y / denom - mean * mean;
            mn[p] = mean;
            rs[p] = rsqrtf(var + GN_EPS);
        }
        float y0 = silu_f((v0.x - mn[0]) * rs[0] * ga0.x + be0.x);
        float y1 = silu_f((v0.y - mn[0]) * rs[0] * ga0.y + be0.y);
        float y2 = silu_f((v0.z - mn[1]) * rs[1] * ga0.z + be0.z);
        float y3 = silu_f((v0.w - mn[1]) * rs[1] * ga0.w + be0.w);
        float y4 = silu_f((v1.x - mn[2]) * rs[2] * ga1.x + be1.x);
        float y5 = silu_f((v1.y - mn[2]) * rs[2] * ga1.y + be1.y);
        float y6 = silu_f((v1.z - mn[3]) * rs[3] * ga1.z + be1.z);
        float y7 = silu_f((v1.w - mn[3]) * rs[3] * ga1.w + be1.w);
        uint4 o;
        o.x = pack2(y0, y1); o.y = pack2(y2, y3); o.z = pack2(y4, y5); o.w = pack2(y6, y7);
        *(uint4*)(out + (size_t)n * C + seg * 8) = o;
    }
}

__device__ __forceinline__ void gn_apply_bf16_body(
    const u16* __restrict__ x, const int* __restrict__ batch_id,
    const float* __restrict__ stats, const float* __restrict__ cnt,
    const float* __restrict__ gamma, const float* __restrict__ beta,
    u16* __restrict__ out) {
    const int gstride = NBLK * 512;
    for (int idx = blockIdx.x * 512 + threadIdx.x; idx < NN * 8; idx += gstride) {
        int n = idx >> 3, seg = idx & 7;
        int b = batch_id[n];
        float denom = cnt[b] * 2.0f;
        uint4 u = *(const uint4*)(x + (size_t)n * C + seg * 8);
        float4 ga0 = *(const float4*)(gamma + seg * 8);
        float4 ga1 = *(const float4*)(gamma + seg * 8 + 4);
        float4 be0 = *(const float4*)(beta + seg * 8);
        float4 be1 = *(const float4*)(beta + seg * 8 + 4);
        float mn[4], rs[4];
#pragma unroll
        for (int p = 0; p < 4; ++p) {
            float2 st = *(const float2*)(stats + (b * NGROUP + seg * 4 + p) * 2);
            float mean = st.x / denom;
            float var = st.y / denom - mean * mean;
            mn[p] = mean;
            rs[p] = rsqrtf(var + GN_EPS);
        }
        float v0 = bf2f(u.x & 0xffff), v1 = bf2f(u.x >> 16);
        float v2 = bf2f(u.y & 0xffff), v3 = bf2f(u.y >> 16);
        float v4 = bf2f(u.z & 0xffff), v5 = bf2f(u.z >> 16);
        float v6 = bf2f(u.w & 0xffff), v7 = bf2f(u.w >> 16);
        float y0 = silu_f((v0 - mn[0]) * rs[0] * ga0.x + be0.x);
        float y1 = silu_f((v1 - mn[0]) * rs[0] * ga0.y + be0.y);
        float y2 = silu_f((v2 - mn[1]) * rs[1] * ga0.z + be0.z);
        float y3 = silu_f((v3 - mn[1]) * rs[1] * ga0.w + be0.w);
        float y4 = silu_f((v4 - mn[2]) * rs[2] * ga1.x + be1.x);
        float y5 = silu_f((v5 - mn[2]) * rs[2] * ga1.y + be1.y);
        float y6 = silu_f((v6 - mn[3]) * rs[3] * ga1.z + be1.z);
        float y7 = silu_f((v7 - mn[3]) * rs[3] * ga1.w + be1.w);
        uint4 o;
        o.x = pack2(y0, y1); o.y = pack2(y2, y3); o.z = pack2(y4, y5); o.w = pack2(y6, y7);
        *(uint4*)(out + (size_t)n * C + seg * 8) = o;
    }
}

// ---------- the single mega kernel (software grid barriers) ----------
__global__ __launch_bounds__(512, 4) void mega_kernel(MegaArgs a) {
    __shared__ u16 Wbuf[6 * 64 * 64]; // 49152 B (also reused as float scratch)
    float* shf = (float*)Wbuf;
    const int bid = blockIdx.x;
    const int t = threadIdx.x;

    // ================= P0: W-prep / time-MLP / gn1 stats =================
    if (bid < 108) {
        const int per = KNB * C * C; // 110592
        int e0 = (bid * 512 + t) * 4;
#pragma unroll
        for (int d = 0; d < 4; ++d) {
            int idx = e0 + d;
            const float* src = (idx < per) ? a.W1 : a.W2;
            u16* dst = (idx < per) ? a.Wb1 : a.Wb2;
            int e = (idx < per) ? idx : idx - per;
            int k = e >> 12;
            int rem = e & 4095;
            int co = rem >> 6;
            int ci = rem & 63;
            dst[e] = f2bf(src[(k * C + ci) * C + co]);
        }
    } else if (bid < 116) {
        int b = bid - 108;
        int co = t & 63, seg = t >> 6; // seg 0..7
        float acc = 0.f;
        for (int i = 0; i < 64; ++i) {
            int e = seg * 64 + i;
            float v = a.time_emb[b * EMB + e];
            acc += silu_f(v) * a.Wt[e * C + co];
        }
        shf[t] = acc;
        __syncthreads();
        if (t < 64) {
            float s = a.bt[t];
#pragma unroll
            for (int j = 0; j < 8; ++j) s += shf[t + 64 * j];
            a.tvec[b * C + t] = s;
        }
    }
    __syncthreads();
    // gn1 stats: every block handles 256 nodes
    {
        for (int i = t; i < 520; i += 512) shf[i] = 0.f;
        __syncthreads();
        const int n0s = bid * 256;
        const int c4 = t & 15, r = t >> 4; // r 0..31
        float s0 = 0.f, ss0 = 0.f, s1 = 0.f, ss1 = 0.f, c = 0.f;
        int cur = -1;
        for (int i = 0; i < 8; ++i) {
            int n = n0s + i * 32 + r;
            int b = a.batch_id[n];
            if (b != cur) {
                if (cur >= 0) {
                    int g0 = 2 * c4;
                    atomicAdd(&shf[(cur * NGROUP + g0) * 2 + 0], s0);
                    atomicAdd(&shf[(cur * NGROUP + g0) * 2 + 1], ss0);
                    atomicAdd(&shf[(cur * NGROUP + g0 + 1) * 2 + 0], s1);
                    atomicAdd(&shf[(cur * NGROUP + g0 + 1) * 2 + 1], ss1);
                    if (c4 == 0) atomicAdd(&shf[512 + cur], c);
                }
                cur = b; s0 = ss0 = s1 = ss1 = c = 0.f;
            }
            float4 v = *(const float4*)(a.x + (size_t)n * C + c4 * 4);
            s0 += v.x + v.y;  ss0 += v.x * v.x + v.y * v.y;
            s1 += v.z + v.w;  ss1 += v.z * v.z + v.w * v.w;
            c += 1.f;
        }
        {
            int g0 = 2 * c4;
            atomicAdd(&shf[(cur * NGROUP + g0) * 2 + 0], s0);
            atomicAdd(&shf[(cur * NGROUP + g0) * 2 + 1], ss0);
            atomicAdd(&shf[(cur * NGROUP + g0 + 1) * 2 + 0], s1);
            atomicAdd(&shf[(cur * NGROUP + g0 + 1) * 2 + 1], ss1);
            if (c4 == 0) atomicAdd(&shf[512 + cur], c);
        }
        __syncthreads();
        if (t < 512 && shf[t] != 0.f) atomicAdd(&a.stats1[t], shf[t]);
        if (t < 8 && shf[512 + t] != 0.f) atomicAdd(&a.cnt1[t], shf[512 + t]);
    }

    grid_barrier(a.bar + 0);
    // ================= P1: gn1 apply x -> h1 (bf16) =================
    gn_apply_f32_body(a.x, a.batch_id, a.stats1, a.cnt1, a.g1, a.be1, a.h1);

    grid_barrier(a.bar + 16);
    // ================= P2: conv1 (+temb, +fused gn2 stats) -> h2 bf16 =================
    conv_body<true, true, false>(a.h1, a.neigh, a.Wb1, a.b1, a.tvec, a.batch_id,
                                 nullptr, (void*)a.h2, a.stats2, a.cnt2, Wbuf);

    grid_barrier(a.bar + 32);
    // ================= P3: gn2 apply h2 -> h3 (bf16) =================
    gn_apply_bf16_body(a.h2, a.batch_id, a.stats2, a.cnt2, a.g2, a.be2, a.h3);

    grid_barrier(a.bar + 48);
    // ================= P4: conv2 + residual -> out fp32 =================
    conv_body<false, false, true>(a.h3, a.neigh, a.Wb2, a.b2, nullptr, a.batch_id,
                                  a.x, (void*)a.out, nullptr, nullptr, Wbuf);
}

extern "C" void kernel_launch(void* const* d_in, const int* in_sizes, int n_in,
                              void* d_out, int out_size, void* d_ws, size_t ws_size,
                              hipStream_t stream) {
    char* ws = (char*)d_ws;
    MegaArgs a;
    a.x        = (const float*)d_in[0];
    a.time_emb = (const float*)d_in[1];
    a.batch_id = (const int*)d_in[2];
    a.neigh    = (const int*)d_in[3];
    a.g1       = (const float*)d_in[4];
    a.be1      = (const float*)d_in[5];
    a.W1       = (const float*)d_in[6];
    a.b1       = (const float*)d_in[7];
    a.Wt       = (const float*)d_in[8];
    a.bt       = (const float*)d_in[9];
    a.g2       = (const float*)d_in[10];
    a.be2      = (const float*)d_in[11];
    a.W2       = (const float*)d_in[12];
    a.b2       = (const float*)d_in[13];
    a.h1     = (u16*)(ws + 0);            // 16 MB
    a.h2     = (u16*)(ws + 16777216);     // 16 MB
    a.h3     = (u16*)(ws + 33554432);     // 16 MB
    a.Wb1    = (u16*)(ws + 50331648);     // 221184 B
    a.Wb2    = (u16*)(ws + 50552832);     // 221184 B
    a.tvec   = (float*)(ws + 50774016);   // 2048 B, ends 50776064
    a.stats1 = (float*)(ws + 50776064);   // 512 f, ends 50778112
    a.cnt1   = a.stats1 + 512;            // 8 f,   ends 50778144
    a.stats2 = a.cnt1 + 8;                // 512 f, ends 50780192
    a.cnt2   = a.stats2 + 512;            // 8 f,   ends 50780224
    a.bar    = (unsigned*)(ws + 50780224); // 64 u32, ends 50780480 (covered by memset)
    a.out    = (float*)d_out;

    // zero stats (1040 floats) + barrier counters (64 uints) = 4416 bytes contiguous
    hipMemsetAsync(ws + 50776064, 0, 4416, stream);
    mega_kernel<<<NBLK, 512, 0, stream>>>(a);
}

// Round 9
// 460.614 us; speedup vs baseline: 1.3491x; 1.1148x over previous
//
#include <hip/hip_runtime.h>
#include <hip/hip_bf16.h>
#include <cstdint>

typedef unsigned short u16;
typedef __attribute__((ext_vector_type(8))) __bf16 bf16x8;
typedef __attribute__((ext_vector_type(4))) float f32x4;

#define NN 131072
#define C 64
#define KNB 27
#define EMB 512
#define NGROUP 32
#define GN_EPS 1e-5f
#define NBLK 512

__device__ __forceinline__ void gload_lds16(const void* gsrc, void* ldsdst) {
    __builtin_amdgcn_global_load_lds(
        (const __attribute__((address_space(1))) char*)(unsigned long long)(uintptr_t)gsrc,
        (__attribute__((address_space(3))) char*)(unsigned int)(uintptr_t)ldsdst,
        16, 0, 0);
}

__device__ __forceinline__ float silu_f(float x) {
    return x / (1.0f + __expf(-x));
}

__device__ __forceinline__ u16 f2bf(float x) {
    __hip_bfloat16 h = __float2bfloat16(x);
    return __builtin_bit_cast(u16, h);
}

__device__ __forceinline__ float bf2f(u16 h) {
    unsigned u = ((unsigned)h) << 16;
    return __builtin_bit_cast(float, u);
}

__device__ __forceinline__ unsigned pack2(float a, float b) {
    return (unsigned)f2bf(a) | ((unsigned)f2bf(b) << 16);
}

// Software grid barrier with DIRECTIONAL fences:
//  - release fence (wbl2, writeback-only, no invalidate) before arrival -> early
//    arrivers do NOT blow away late blocks' L2 working set;
//  - relaxed spin (no per-poll invalidation);
//  - acquire fence (inv) exactly once, after all blocks arrived (synchronized).
// Safe: grid(512) <= residency capacity (>=2 blocks/CU by LDS/VGPR/waves).
__device__ __forceinline__ void grid_barrier(unsigned* ctr) {
    __syncthreads();
    if (threadIdx.x == 0) {
        __builtin_amdgcn_fence(__ATOMIC_RELEASE, "agent"); // writeback, no inv
        __hip_atomic_fetch_add(ctr, 1u, __ATOMIC_RELAXED, __HIP_MEMORY_SCOPE_AGENT);
        while (__hip_atomic_load(ctr, __ATOMIC_RELAXED, __HIP_MEMORY_SCOPE_AGENT) < NBLK) {
            __builtin_amdgcn_s_sleep(32);
        }
        __builtin_amdgcn_fence(__ATOMIC_ACQUIRE, "agent"); // single invalidate
    }
    __syncthreads();
}

struct MegaArgs {
    const float* x;
    const float* time_emb;
    const int* batch_id;
    const int* neigh;
    const float* g1; const float* be1;
    const float* W1; const float* b1;
    const float* Wt; const float* bt;
    const float* g2; const float* be2;
    const float* W2; const float* b2;
    u16* Wb1; u16* Wb2;
    float* tvec;
    float* stats1; float* cnt1;
    float* stats2; float* cnt2;
    unsigned* bar;
    u16* h1; u16* h2; u16* h3;
    float* out;
};

// ---------- conv body: A gathered to regs (depth-2, mod-3 queue), W phase-LDS ----------
// Block 512 thr (8 waves), wave = 32 nodes x 64 co, block = 256 nodes.
template <bool ADD_T, bool FUSE_STATS, bool OUT_F32_RES>
__device__ __forceinline__ void conv_body(
    const u16* __restrict__ act, const int* __restrict__ neigh,
    const u16* __restrict__ Wb, const float* __restrict__ bias,
    const float* __restrict__ tvec, const int* __restrict__ batch_id,
    const float* __restrict__ resid, void* __restrict__ outp,
    float* __restrict__ stats, float* __restrict__ cnt, u16* Wbuf) {
    float* shs = (float*)Wbuf;
    const int tid = threadIdx.x;
    const int w = tid >> 6, lane = tid & 63;
    const int q = lane >> 4, m = lane & 15;
    const int n0 = blockIdx.x * 256;
    const int nw = n0 + w * 32;

    const int* nrow0 = neigh + (size_t)(nw + m) * KNB;
    const int* nrow1 = neigh + (size_t)(nw + 16 + m) * KNB;

    f32x4 acc[2][4] = {};
    bf16x8 aB[3][2][2];
    int offn0, offn1;

    {
        int o0 = nrow0[0] * C, o1 = nrow1[0] * C;
        aB[0][0][0] = *(const bf16x8*)(act + o0 + q * 8);
        aB[0][0][1] = *(const bf16x8*)(act + o0 + 32 + q * 8);
        aB[0][1][0] = *(const bf16x8*)(act + o1 + q * 8);
        aB[0][1][1] = *(const bf16x8*)(act + o1 + 32 + q * 8);
        o0 = nrow0[1] * C; o1 = nrow1[1] * C;
        aB[1][0][0] = *(const bf16x8*)(act + o0 + q * 8);
        aB[1][0][1] = *(const bf16x8*)(act + o0 + 32 + q * 8);
        aB[1][1][0] = *(const bf16x8*)(act + o1 + q * 8);
        aB[1][1][1] = *(const bf16x8*)(act + o1 + 32 + q * 8);
        offn0 = nrow0[2] * C;
        offn1 = nrow1[2] * C;
    }

    // phases of 6/6/6/6/3 k-slices; phase starts divisible by 3 -> k%3 == sI%3
#pragma unroll
    for (int phase = 0; phase < 5; ++phase) {
        const int k0 = phase * 6;
        const int nk = (phase == 4) ? 3 : 6;
        if (phase) __syncthreads(); // prior phase's Wbuf reads done
        const int total = nk * 512;
#pragma unroll
        for (int it = 0; it < 6; ++it) {
            int cb = it * 512 + w * 64; // wave-uniform chunk base
            if (cb < total) {
                int cc = cb + lane;
                int rr = cc >> 3;
                int pos = cc & 7;
                int srcc = pos ^ (rr & 7);
                gload_lds16(Wb + (((k0 << 6) + rr) << 6) + (srcc << 3), Wbuf + cb * 8);
            }
        }
        __syncthreads(); // W visible

#pragma unroll
        for (int sI = 0; sI < nk; ++sI) {
            const int k = k0 + sI;
            const int use = sI % 3;        // == k%3
            const int nxt = (sI + 2) % 3;  // == (k+2)%3
            if (k + 2 < KNB) {
                aB[nxt][0][0] = *(const bf16x8*)(act + offn0 + q * 8);
                aB[nxt][0][1] = *(const bf16x8*)(act + offn0 + 32 + q * 8);
                aB[nxt][1][0] = *(const bf16x8*)(act + offn1 + q * 8);
                aB[nxt][1][1] = *(const bf16x8*)(act + offn1 + 32 + q * 8);
            }
            if (k + 3 < KNB) {
                offn0 = nrow0[k + 3] * C;
                offn1 = nrow1[k + 3] * C;
            }
            const u16* wsl = Wbuf + sI * 4096;
#pragma unroll
            for (int kk = 0; kk < 2; ++kk) {
#pragma unroll
                for (int j = 0; j < 4; ++j) {
                    const int co = j * 16 + m;
                    const int lc = kk * 4 + q;
                    bf16x8 b = *(const bf16x8*)(wsl + (co << 6) + ((lc ^ (co & 7)) << 3));
                    acc[0][j] = __builtin_amdgcn_mfma_f32_16x16x32_bf16(aB[use][0][kk], b, acc[0][j], 0, 0, 0);
                    acc[1][j] = __builtin_amdgcn_mfma_f32_16x16x32_bf16(aB[use][1][kk], b, acc[1][j], 0, 0, 0);
                }
            }
        }
    }

    // ---- epilogue: bias (+temb), store; D: col=m (co j*16+m), row=q*4+reg ----
    float bs[4];
#pragma unroll
    for (int j = 0; j < 4; ++j) bs[j] = bias[j * 16 + m];

#pragma unroll
    for (int s = 0; s < 2; ++s) {
#pragma unroll
        for (int reg = 0; reg < 4; ++reg) {
            const int n = nw + s * 16 + q * 4 + reg;
            int b = 0;
            if (ADD_T) b = batch_id[n];
#pragma unroll
            for (int j = 0; j < 4; ++j) {
                const int co = j * 16 + m;
                float v = acc[s][j][reg] + bs[j];
                if (ADD_T) v += tvec[b * C + co];
                acc[s][j][reg] = v;
                if (OUT_F32_RES) {
                    ((float*)outp)[(size_t)n * C + co] = v + resid[(size_t)n * C + co];
                } else {
                    ((u16*)outp)[(size_t)n * C + co] = f2bf(v);
                }
            }
        }
    }

    if (FUSE_STATS) {
        __syncthreads(); // all waves done with Wbuf -> reuse as stats scratch
        for (int i = tid; i < 520; i += 512) shs[i] = 0.f;
        __syncthreads();
        const int blo = batch_id[nw], bhi = batch_id[nw + 31];
        if (blo == bhi) {
#pragma unroll
            for (int j = 0; j < 4; ++j) {
                float s = 0.f, ss = 0.f;
#pragma unroll
                for (int sq = 0; sq < 2; ++sq)
#pragma unroll
                    for (int reg = 0; reg < 4; ++reg) {
                        float v = acc[sq][j][reg];
                        s += v; ss += v * v;
                    }
                s += __shfl_xor(s, 16, 64);  ss += __shfl_xor(ss, 16, 64);
                s += __shfl_xor(s, 32, 64);  ss += __shfl_xor(ss, 32, 64);
                s += __shfl_xor(s, 1, 64);   ss += __shfl_xor(ss, 1, 64);
                if (q == 0 && (m & 1) == 0) {
                    int g = (j * 16 + m) >> 1;
                    atomicAdd(&shs[(blo * NGROUP + g) * 2 + 0], s);
                    atomicAdd(&shs[(blo * NGROUP + g) * 2 + 1], ss);
                }
            }
        } else {
#pragma unroll
            for (int sq = 0; sq < 2; ++sq)
#pragma unroll
                for (int reg = 0; reg < 4; ++reg) {
                    int b = batch_id[nw + sq * 16 + q * 4 + reg];
#pragma unroll
                    for (int j = 0; j < 4; ++j) {
                        int g = (j * 16 + m) >> 1;
                        float v = acc[sq][j][reg];
                        atomicAdd(&shs[(b * NGROUP + g) * 2 + 0], v);
                        atomicAdd(&shs[(b * NGROUP + g) * 2 + 1], v * v);
                    }
                }
        }
        if (tid < 256) atomicAdd(&shs[512 + batch_id[n0 + tid]], 1.0f);
        __syncthreads();
        if (tid < 512 && shs[tid] != 0.f) atomicAdd(&stats[tid], shs[tid]);
        if (tid < 8 && shs[512 + tid] != 0.f) atomicAdd(&cnt[tid], shs[512 + tid]);
    }
}

// ---------- gn apply bodies (grid-stride, 8 ch/item) ----------
__device__ __forceinline__ void gn_apply_f32_body(
    const float* __restrict__ x, const int* __restrict__ batch_id,
    const float* __restrict__ stats, const float* __restrict__ cnt,
    const float* __restrict__ gamma, const float* __restrict__ beta,
    u16* __restrict__ out) {
    const int gstride = NBLK * 512;
    for (int idx = blockIdx.x * 512 + threadIdx.x; idx < NN * 8; idx += gstride) {
        int n = idx >> 3, seg = idx & 7;
        int b = batch_id[n];
        float denom = cnt[b] * 2.0f;
        float4 v0 = *(const float4*)(x + (size_t)n * C + seg * 8);
        float4 v1 = *(const float4*)(x + (size_t)n * C + seg * 8 + 4);
        float4 ga0 = *(const float4*)(gamma + seg * 8);
        float4 ga1 = *(const float4*)(gamma + seg * 8 + 4);
        float4 be0 = *(const float4*)(beta + seg * 8);
        float4 be1 = *(const float4*)(beta + seg * 8 + 4);
        float mn[4], rs[4];
#pragma unroll
        for (int p = 0; p < 4; ++p) {
            float2 st = *(const float2*)(stats + (b * NGROUP + seg * 4 + p) * 2);
            float mean = st.x / denom;
            float var = st.y / denom - mean * mean;
            mn[p] = mean;
            rs[p] = rsqrtf(var + GN_EPS);
        }
        float y0 = silu_f((v0.x - mn[0]) * rs[0] * ga0.x + be0.x);
        float y1 = silu_f((v0.y - mn[0]) * rs[0] * ga0.y + be0.y);
        float y2 = silu_f((v0.z - mn[1]) * rs[1] * ga0.z + be0.z);
        float y3 = silu_f((v0.w - mn[1]) * rs[1] * ga0.w + be0.w);
        float y4 = silu_f((v1.x - mn[2]) * rs[2] * ga1.x + be1.x);
        float y5 = silu_f((v1.y - mn[2]) * rs[2] * ga1.y + be1.y);
        float y6 = silu_f((v1.z - mn[3]) * rs[3] * ga1.z + be1.z);
        float y7 = silu_f((v1.w - mn[3]) * rs[3] * ga1.w + be1.w);
        uint4 o;
        o.x = pack2(y0, y1); o.y = pack2(y2, y3); o.z = pack2(y4, y5); o.w = pack2(y6, y7);
        *(uint4*)(out + (size_t)n * C + seg * 8) = o;
    }
}

__device__ __forceinline__ void gn_apply_bf16_body(
    const u16* __restrict__ x, const int* __restrict__ batch_id,
    const float* __restrict__ stats, const float* __restrict__ cnt,
    const float* __restrict__ gamma, const float* __restrict__ beta,
    u16* __restrict__ out) {
    const int gstride = NBLK * 512;
    for (int idx = blockIdx.x * 512 + threadIdx.x; idx < NN * 8; idx += gstride) {
        int n = idx >> 3, seg = idx & 7;
        int b = batch_id[n];
        float denom = cnt[b] * 2.0f;
        uint4 u = *(const uint4*)(x + (size_t)n * C + seg * 8);
        float4 ga0 = *(const float4*)(gamma + seg * 8);
        float4 ga1 = *(const float4*)(gamma + seg * 8 + 4);
        float4 be0 = *(const float4*)(beta + seg * 8);
        float4 be1 = *(const float4*)(beta + seg * 8 + 4);
        float mn[4], rs[4];
#pragma unroll
        for (int p = 0; p < 4; ++p) {
            float2 st = *(const float2*)(stats + (b * NGROUP + seg * 4 + p) * 2);
            float mean = st.x / denom;
            float var = st.y / denom - mean * mean;
            mn[p] = mean;
            rs[p] = rsqrtf(var + GN_EPS);
        }
        float v0 = bf2f(u.x & 0xffff), v1 = bf2f(u.x >> 16);
        float v2 = bf2f(u.y & 0xffff), v3 = bf2f(u.y >> 16);
        float v4 = bf2f(u.z & 0xffff), v5 = bf2f(u.z >> 16);
        float v6 = bf2f(u.w & 0xffff), v7 = bf2f(u.w >> 16);
        float y0 = silu_f((v0 - mn[0]) * rs[0] * ga0.x + be0.x);
        float y1 = silu_f((v1 - mn[0]) * rs[0] * ga0.y + be0.y);
        float y2 = silu_f((v2 - mn[1]) * rs[1] * ga0.z + be0.z);
        float y3 = silu_f((v3 - mn[1]) * rs[1] * ga0.w + be0.w);
        float y4 = silu_f((v4 - mn[2]) * rs[2] * ga1.x + be1.x);
        float y5 = silu_f((v5 - mn[2]) * rs[2] * ga1.y + be1.y);
        float y6 = silu_f((v6 - mn[3]) * rs[3] * ga1.z + be1.z);
        float y7 = silu_f((v7 - mn[3]) * rs[3] * ga1.w + be1.w);
        uint4 o;
        o.x = pack2(y0, y1); o.y = pack2(y2, y3); o.z = pack2(y4, y5); o.w = pack2(y6, y7);
        *(uint4*)(out + (size_t)n * C + seg * 8) = o;
    }
}

// ---------- the single mega kernel (software grid barriers) ----------
__global__ __launch_bounds__(512, 4) void mega_kernel(MegaArgs a) {
    __shared__ u16 Wbuf[6 * 64 * 64]; // 49152 B (also reused as float scratch)
    float* shf = (float*)Wbuf;
    const int bid = blockIdx.x;
    const int t = threadIdx.x;

    // ================= P0: W-prep / time-MLP / gn1 stats =================
    if (bid < 108) {
        const int per = KNB * C * C; // 110592
        int e0 = (bid * 512 + t) * 4;
#pragma unroll
        for (int d = 0; d < 4; ++d) {
            int idx = e0 + d;
            const float* src = (idx < per) ? a.W1 : a.W2;
            u16* dst = (idx < per) ? a.Wb1 : a.Wb2;
            int e = (idx < per) ? idx : idx - per;
            int k = e >> 12;
            int rem = e & 4095;
            int co = rem >> 6;
            int ci = rem & 63;
            dst[e] = f2bf(src[(k * C + ci) * C + co]);
        }
    } else if (bid < 116) {
        int b = bid - 108;
        int co = t & 63, seg = t >> 6; // seg 0..7
        float acc = 0.f;
        for (int i = 0; i < 64; ++i) {
            int e = seg * 64 + i;
            float v = a.time_emb[b * EMB + e];
            acc += silu_f(v) * a.Wt[e * C + co];
        }
        shf[t] = acc;
        __syncthreads();
        if (t < 64) {
            float s = a.bt[t];
#pragma unroll
            for (int j = 0; j < 8; ++j) s += shf[t + 64 * j];
            a.tvec[b * C + t] = s;
        }
    }
    __syncthreads();
    // gn1 stats: every block handles 256 nodes
    {
        for (int i = t; i < 520; i += 512) shf[i] = 0.f;
        __syncthreads();
        const int n0s = bid * 256;
        const int c4 = t & 15, r = t >> 4; // r 0..31
        float s0 = 0.f, ss0 = 0.f, s1 = 0.f, ss1 = 0.f, c = 0.f;
        int cur = -1;
        for (int i = 0; i < 8; ++i) {
            int n = n0s + i * 32 + r;
            int b = a.batch_id[n];
            if (b != cur) {
                if (cur >= 0) {
                    int g0 = 2 * c4;
                    atomicAdd(&shf[(cur * NGROUP + g0) * 2 + 0], s0);
                    atomicAdd(&shf[(cur * NGROUP + g0) * 2 + 1], ss0);
                    atomicAdd(&shf[(cur * NGROUP + g0 + 1) * 2 + 0], s1);
                    atomicAdd(&shf[(cur * NGROUP + g0 + 1) * 2 + 1], ss1);
                    if (c4 == 0) atomicAdd(&shf[512 + cur], c);
                }
                cur = b; s0 = ss0 = s1 = ss1 = c = 0.f;
            }
            float4 v = *(const float4*)(a.x + (size_t)n * C + c4 * 4);
            s0 += v.x + v.y;  ss0 += v.x * v.x + v.y * v.y;
            s1 += v.z + v.w;  ss1 += v.z * v.z + v.w * v.w;
            c += 1.f;
        }
        {
            int g0 = 2 * c4;
            atomicAdd(&shf[(cur * NGROUP + g0) * 2 + 0], s0);
            atomicAdd(&shf[(cur * NGROUP + g0) * 2 + 1], ss0);
            atomicAdd(&shf[(cur * NGROUP + g0 + 1) * 2 + 0], s1);
            atomicAdd(&shf[(cur * NGROUP + g0 + 1) * 2 + 1], ss1);
            if (c4 == 0) atomicAdd(&shf[512 + cur], c);
        }
        __syncthreads();
        if (t < 512 && shf[t] != 0.f) atomicAdd(&a.stats1[t], shf[t]);
        if (t < 8 && shf[512 + t] != 0.f) atomicAdd(&a.cnt1[t], shf[512 + t]);
    }

    grid_barrier(a.bar + 0);
    // ================= P1: gn1 apply x -> h1 (bf16) =================
    gn_apply_f32_body(a.x, a.batch_id, a.stats1, a.cnt1, a.g1, a.be1, a.h1);

    grid_barrier(a.bar + 16);
    // ================= P2: conv1 (+temb, +fused gn2 stats) -> h2 bf16 =================
    conv_body<true, true, false>(a.h1, a.neigh, a.Wb1, a.b1, a.tvec, a.batch_id,
                                 nullptr, (void*)a.h2, a.stats2, a.cnt2, Wbuf);

    grid_barrier(a.bar + 32);
    // ================= P3: gn2 apply h2 -> h3 (bf16) =================
    gn_apply_bf16_body(a.h2, a.batch_id, a.stats2, a.cnt2, a.g2, a.be2, a.h3);

    grid_barrier(a.bar + 48);
    // ================= P4: conv2 + residual -> out fp32 =================
    conv_body<false, false, true>(a.h3, a.neigh, a.Wb2, a.b2, nullptr, a.batch_id,
                                  a.x, (void*)a.out, nullptr, nullptr, Wbuf);
}

extern "C" void kernel_launch(void* const* d_in, const int* in_sizes, int n_in,
                              void* d_out, int out_size, void* d_ws, size_t ws_size,
                              hipStream_t stream) {
    char* ws = (char*)d_ws;
    MegaArgs a;
    a.x        = (const float*)d_in[0];
    a.time_emb = (const float*)d_in[1];
    a.batch_id = (const int*)d_in[2];
    a.neigh    = (const int*)d_in[3];
    a.g1       = (const float*)d_in[4];
    a.be1      = (const float*)d_in[5];
    a.W1       = (const float*)d_in[6];
    a.b1       = (const float*)d_in[7];
    a.Wt       = (const float*)d_in[8];
    a.bt       = (const float*)d_in[9];
    a.g2       = (const float*)d_in[10];
    a.be2      = (const float*)d_in[11];
    a.W2       = (const float*)d_in[12];
    a.b2       = (const float*)d_in[13];
    a.h1     = (u16*)(ws + 0);            // 16 MB
    a.h2     = (u16*)(ws + 16777216);     // 16 MB
    a.h3     = (u16*)(ws + 33554432);     // 16 MB
    a.Wb1    = (u16*)(ws + 50331648);     // 221184 B
    a.Wb2    = (u16*)(ws + 50552832);     // 221184 B
    a.tvec   = (float*)(ws + 50774016);   // 2048 B, ends 50776064
    a.stats1 = (float*)(ws + 50776064);   // 512 f, ends 50778112
    a.cnt1   = a.stats1 + 512;            // 8 f,   ends 50778144
    a.stats2 = a.cnt1 + 8;                // 512 f, ends 50780192
    a.cnt2   = a.stats2 + 512;            // 8 f,   ends 50780224
    a.bar    = (unsigned*)(ws + 50780224); // 64 u32, ends 50780480 (covered by memset)
    a.out    = (float*)d_out;

    // zero stats (1040 floats) + barrier counters (64 uints) = 4416 bytes contiguous
    hipMemsetAsync(ws + 50776064, 0, 4416, stream);
    mega_kernel<<<NBLK, 512, 0, stream>>>(a);
}